// Round 6
// baseline (294.007 us; speedup 1.0000x reference)
//
#include <hip/hip_runtime.h>

#define NB 256
#define NT 1024
#define NL 64
#define PB 128  // pair-blocks per direction

typedef __fp16 h2v __attribute__((ext_vector_type(2)));

__device__ __forceinline__ float rfl_f(float v) {
  return __builtin_bit_cast(float, __builtin_amdgcn_readfirstlane(__builtin_bit_cast(int, v)));
}

// partner = value from lane^1, via DPP quad_perm [1,0,3,2] (VALU, no LDS pipe)
__device__ __forceinline__ float dpp_xor1(float v) {
  int i = __builtin_bit_cast(int, v);
  int r = __builtin_amdgcn_update_dpp(i, i, 0xB1, 0xF, 0xF, false);
  return __builtin_bit_cast(float, r);
}

// Phase 1: pack (w, partner) -> f16x2, write one b32 to this chain's LDS
// buffer, issue the 8 uniform-address (broadcast) b128 reads. P0..P7 stay
// live for phase 2. The two chains' phases interleave so each chain's LDS
// round-trip hides under the other chain's fdot2 work.
#define CRF_BCAST(PFX, W, LB, LBV)                                            \
  float PFX##wn = dpp_xor1(W);                                                \
  h2v PFX##pk = __builtin_amdgcn_cvt_pkrtz(W, PFX##wn);                       \
  LB[slot] = __builtin_bit_cast(int, PFX##pk);                                \
  int4 PFX##P0 = LBV[0], PFX##P1 = LBV[1], PFX##P2 = LBV[2], PFX##P3 = LBV[3];\
  int4 PFX##P4 = LBV[4], PFX##P5 = LBV[5], PFX##P6 = LBV[6], PFX##P7 = LBV[7];

#define DOT4P(PFX, P, B)                                                      \
  PFX##s0 = __builtin_amdgcn_fdot2(__builtin_bit_cast(h2v, (P).x), R[(B) + 0], PFX##s0, false); \
  PFX##s1 = __builtin_amdgcn_fdot2(__builtin_bit_cast(h2v, (P).y), R[(B) + 1], PFX##s1, false); \
  PFX##s2 = __builtin_amdgcn_fdot2(__builtin_bit_cast(h2v, (P).z), R[(B) + 2], PFX##s2, false); \
  PFX##s3 = __builtin_amdgcn_fdot2(__builtin_bit_cast(h2v, (P).w), R[(B) + 3], PFX##s3, false);

// Phase 2: uniform renorm scale K = 2^(3-e5) from pair0's f16 exponent (pure
// VALU, no readfirstlane), 32 fdot2 against the SHARED table R, state update.
// e2 accumulates raw e5; the -3/step is folded in once at the end.
#define CRF_MATVEC(PFX, W, E2, EF)                                            \
  int PFX##e5 = (PFX##P0.x >> 10) & 0x1f;                                     \
  float PFX##K = __builtin_bit_cast(float, (130 - PFX##e5) << 23);            \
  E2 += PFX##e5;                                                              \
  float PFX##s0 = 0.f, PFX##s1 = 0.f, PFX##s2 = 0.f, PFX##s3 = 0.f;           \
  DOT4P(PFX, PFX##P0, 0) DOT4P(PFX, PFX##P1, 4)                               \
  DOT4P(PFX, PFX##P2, 8) DOT4P(PFX, PFX##P3, 12)                              \
  DOT4P(PFX, PFX##P4, 16) DOT4P(PFX, PFX##P5, 20)                             \
  DOT4P(PFX, PFX##P6, 24) DOT4P(PFX, PFX##P7, 28)                             \
  W = ((PFX##s0 + PFX##s1) + (PFX##s2 + PFX##s3)) * (PFX##K * (EF));

#define STEP_PAIR(EF0, EF1)                                                   \
  {                                                                           \
    CRF_BCAST(X_, w0, lb0, lbv0)                                              \
    CRF_BCAST(Y_, w1, lb1, lbv1)                                              \
    CRF_MATVEC(X_, w0, e20, EF0)                                              \
    CRF_MATVEC(Y_, w1, e21, EF1)                                              \
  }

// Blocks 0..127: fwd chains of batches (2j,2j+1) — SAME direction => one
// shared R table (batch-independent), so no table spill. Blocks 128..255:
// bwd chains of batches (2j,2j+1). Blocks 256..511: gold path.
__global__ __launch_bounds__(64, 1) void fb_kernel(const float* __restrict__ scores,
                                                   const int* __restrict__ targets,
                                                   const float* __restrict__ start,
                                                   const float* __restrict__ Tm,
                                                   const float* __restrict__ endv,
                                                   float* __restrict__ wsA,
                                                   float* __restrict__ wsB,
                                                   float* __restrict__ wsG) {
  const int lane = threadIdx.x;
  const int bb = blockIdx.x;

  if (bb >= 2 * PB) {  // ---- gold path: one wave per batch ----
    const int b = bb - 2 * PB;
    const int* tg = targets + b * NT;
    const float* sc = scores + (size_t)b * NT * NL;
    float acc = 0.f;
    for (int t = lane; t < NT; t += 64) {
      int c = tg[t];
      acc += sc[t * NL + c];
      if (t > 0) acc += Tm[c * NL + tg[t - 1]];  // T_mat[cur, prev]
    }
#pragma unroll
    for (int off = 32; off > 0; off >>= 1) acc += __shfl_xor(acc, off, 64);
    if (lane == 0) wsG[b] = acc + start[tg[0]] + endv[tg[NT - 1]];
    return;
  }

  __shared__ int4 lds_s[32];  // words 0..63 = chain-X buffer, 64..127 = chain-Y
  int* lb0 = (int*)lds_s;
  int* lb1 = (int*)(lds_s + 16);
  const int4* lbv0 = lds_s;
  const int4* lbv1 = lds_s + 16;
  const int slot = (lane & 1) * 32 + (lane >> 1);  // 2 lanes/bank write -> free

  const bool bwd = bb >= PB;
  const int bp = bwd ? bb - PB : bb;
  const int b0 = 2 * bp, b1 = 2 * bp + 1;
  const float* sc0 = scores + (size_t)b0 * NT * NL;
  const float* sc1 = scores + (size_t)b1 * NT * NL;
  const float LN2 = 0.69314718055994530942f;

  // shared f16x2 table: fwd R[k] = (exp(T[lane][2k]), exp(T[lane][2k+1]))
  //                     bwd R[k] = (exp(T[2k][lane]), exp(T[2k+1][lane]))
  const float* Tb = bwd ? (Tm + lane) : (Tm + lane * NL);
  const int str = bwd ? NL : 1;
  h2v R[32];
#pragma unroll
  for (int k = 0; k < 32; k++)
    R[k] = __builtin_amdgcn_cvt_pkrtz(__expf(Tb[(2 * k) * str]),
                                      __expf(Tb[(2 * k + 1) * str]));

  float w0, w1, m00, m01;
  int e20, e21;
  if (!bwd) {
    float a0 = start[lane] + sc0[lane];
    float a1 = start[lane] + sc1[lane];
    m00 = rfl_f(a0); m01 = rfl_f(a1);
    w0 = __expf(a0 - m00) * 16.f; w1 = __expf(a1 - m01) * 16.f;
  } else {
    float a0 = endv[lane] + sc0[(NT - 1) * NL + lane];
    float a1 = endv[lane] + sc1[(NT - 1) * NL + lane];
    m00 = rfl_f(a0); m01 = rfl_f(a1);
    w0 = __expf(a0 - m00) * 16.f; w1 = __expf(a1 - m01) * 16.f;
  }
  e20 = -4; e21 = -4;

  if (!bwd) {
    float buf0[4], buf1[4];
#pragma unroll
    for (int k = 0; k < 4; k++) {
      buf0[k] = sc0[(1 + k) * NL + lane];
      buf1[k] = sc1[(1 + k) * NL + lane];
    }
    for (int i = 0; i < 128; i++) {  // 512 steps: t = 1..512
      float nb0[4], nb1[4];
      int tf = 5 + 4 * i;  // prefetch (max 513..516 < 1024)
#pragma unroll
      for (int k = 0; k < 4; k++) {
        nb0[k] = sc0[(tf + k) * NL + lane];
        nb1[k] = sc1[(tf + k) * NL + lane];
      }
      float Ev0[4], Ev1[4];
#pragma unroll
      for (int k = 0; k < 4; k++) {
        Ev0[k] = __expf(buf0[k]);  // off critical chain
        Ev1[k] = __expf(buf1[k]);
      }
      STEP_PAIR(Ev0[0], Ev1[0])
      STEP_PAIR(Ev0[1], Ev1[1])
      STEP_PAIR(Ev0[2], Ev1[2])
      STEP_PAIR(Ev0[3], Ev1[3])
#pragma unroll
      for (int k = 0; k < 4; k++) {
        buf0[k] = nb0[k];
        buf1[k] = nb1[k];
      }
    }
    // alpha_512, transposed [state][batch]; 512 steps: fold -3/step ledger.
    wsA[lane * NB + b0] = m00 + (float)(e20 - 3 * 512) * LN2 + __logf(w0);
    wsA[lane * NB + b1] = m01 + (float)(e21 - 3 * 512) * LN2 + __logf(w1);
  } else {
    float buf0[4], buf1[4];
#pragma unroll
    for (int k = 0; k < 4; k++) {
      buf0[k] = sc0[(1022 - k) * NL + lane];
      buf1[k] = sc1[(1022 - k) * NL + lane];
    }
    for (int i = 0; i < 127; i++) {  // 508 steps: te = 1022..515
      float nb0[4], nb1[4];
      int tb = 1018 - 4 * i;  // prefetch (min 514..511 >= 0)
#pragma unroll
      for (int k = 0; k < 4; k++) {
        nb0[k] = sc0[(tb - k) * NL + lane];
        nb1[k] = sc1[(tb - k) * NL + lane];
      }
      float Ev0[4], Ev1[4];
#pragma unroll
      for (int k = 0; k < 4; k++) {
        Ev0[k] = __expf(buf0[k]);
        Ev1[k] = __expf(buf1[k]);
      }
      STEP_PAIR(Ev0[0], Ev1[0])
      STEP_PAIR(Ev0[1], Ev1[1])
      STEP_PAIR(Ev0[2], Ev1[2])
      STEP_PAIR(Ev0[3], Ev1[3])
#pragma unroll
      for (int k = 0; k < 4; k++) {
        buf0[k] = nb0[k];
        buf1[k] = nb1[k];
      }
    }
    // tails: buf = emits te = 514, 513 (slots 0,1); then final E=1 step.
    {
      float E0 = __expf(buf0[0]), E1 = __expf(buf1[0]);
      STEP_PAIR(E0, E1)
    }
    {
      float E0 = __expf(buf0[1]), E1 = __expf(buf1[1]);
      STEP_PAIR(E0, E1)
    }
    STEP_PAIR(1.0f, 1.0f)  // matvec-only -> beta_512 (emit_512 is alpha-side)
    // beta_512, transposed; 511 steps: fold -3/step ledger.
    wsB[lane * NB + b0] = m00 + (float)(e20 - 3 * 511) * LN2 + __logf(w0);
    wsB[lane * NB + b1] = m01 + (float)(e21 - 3 * 511) * LN2 + __logf(w1);
  }
}

// thread b handles batch b: lse over 64 states (coalesced via transposed ws layout),
// subtract gold, block-reduce mean.
__global__ __launch_bounds__(256) void combine_kernel(const float* __restrict__ wsA,
                                                      const float* __restrict__ wsB,
                                                      const float* __restrict__ wsG,
                                                      float* __restrict__ out) {
  const int b = threadIdx.x;
  float m = -INFINITY;
#pragma unroll
  for (int j = 0; j < NL; j++) m = fmaxf(m, wsA[j * NB + b] + wsB[j * NB + b]);
  float s = 0.f;
#pragma unroll
  for (int j = 0; j < NL; j++) s += __expf(wsA[j * NB + b] + wsB[j * NB + b] - m);
  float loss = (m + __logf(s)) - wsG[b];
#pragma unroll
  for (int off = 32; off > 0; off >>= 1) loss += __shfl_xor(loss, off, 64);
  __shared__ float red[4];
  if ((b & 63) == 0) red[b >> 6] = loss;
  __syncthreads();
  if (b == 0) out[0] = (red[0] + red[1] + red[2] + red[3]) * (1.0f / NB);
}

extern "C" void kernel_launch(void* const* d_in, const int* in_sizes, int n_in,
                              void* d_out, int out_size, void* d_ws, size_t ws_size,
                              hipStream_t stream) {
  const float* scores = (const float*)d_in[0];
  const int* targets = (const int*)d_in[1];
  const float* start = (const float*)d_in[2];
  const float* Tm = (const float*)d_in[3];
  const float* endv = (const float*)d_in[4];
  float* out = (float*)d_out;

  float* wsA = (float*)d_ws;       // [NL*NB] alpha_512, transposed [state][batch]
  float* wsB = wsA + NB * NL;      // [NL*NB] beta_512, transposed
  float* wsG = wsB + NB * NL;      // [NB] gold path scores

  fb_kernel<<<2 * PB + NB, 64, 0, stream>>>(scores, targets, start, Tm, endv, wsA, wsB, wsG);
  combine_kernel<<<1, 256, 0, stream>>>(wsA, wsB, wsG, out);
}

// Round 7
// 231.864 us; speedup vs baseline: 1.2680x; 1.2680x over previous
//
#include <hip/hip_runtime.h>

#define NB 256
#define NT 1024
#define NL 64
#define PB 128  // pair-blocks per direction

typedef __fp16 h2v __attribute__((ext_vector_type(2)));

__device__ __forceinline__ float rfl_f(float v) {
  return __builtin_bit_cast(float, __builtin_amdgcn_readfirstlane(__builtin_bit_cast(int, v)));
}

// partner = value from lane^1, via DPP quad_perm [1,0,3,2] (VALU, no LDS pipe)
__device__ __forceinline__ float dpp_xor1(float v) {
  int i = __builtin_bit_cast(int, v);
  int r = __builtin_amdgcn_update_dpp(i, i, 0xB1, 0xF, 0xF, false);
  return __builtin_bit_cast(float, r);
}

// Phase 1: pack (w, partner) -> f16x2, write one b32 to this chain's LDS
// buffer, issue the 8 uniform-address (broadcast) b128 reads. P0..P7 stay
// live for phase 2.
#define CRF_BCAST(PFX, W, LB, LBV)                                            \
  float PFX##wn = dpp_xor1(W);                                                \
  h2v PFX##pk = __builtin_amdgcn_cvt_pkrtz(W, PFX##wn);                       \
  LB[slot] = __builtin_bit_cast(int, PFX##pk);                                \
  int4 PFX##P0 = LBV[0], PFX##P1 = LBV[1], PFX##P2 = LBV[2], PFX##P3 = LBV[3];\
  int4 PFX##P4 = LBV[4], PFX##P5 = LBV[5], PFX##P6 = LBV[6], PFX##P7 = LBV[7];

#define DOT4P(PFX, P, B)                                                      \
  PFX##s0 = __builtin_amdgcn_fdot2(__builtin_bit_cast(h2v, (P).x), R[(B) + 0], PFX##s0, false); \
  PFX##s1 = __builtin_amdgcn_fdot2(__builtin_bit_cast(h2v, (P).y), R[(B) + 1], PFX##s1, false); \
  PFX##s2 = __builtin_amdgcn_fdot2(__builtin_bit_cast(h2v, (P).z), R[(B) + 2], PFX##s2, false); \
  PFX##s3 = __builtin_amdgcn_fdot2(__builtin_bit_cast(h2v, (P).w), R[(B) + 3], PFX##s3, false);

// Phase 2: uniform renorm scale K = 2^(3-e5) from pair0's f16 exponent (pure
// VALU, no readfirstlane), 32 fdot2 against the SHARED table R, state update.
// e2 accumulates raw e5; the -3/step is folded in once at the end.
#define CRF_MATVEC(PFX, W, E2, EF)                                            \
  int PFX##e5 = (PFX##P0.x >> 10) & 0x1f;                                     \
  float PFX##K = __builtin_bit_cast(float, (130 - PFX##e5) << 23);            \
  E2 += PFX##e5;                                                              \
  float PFX##s0 = 0.f, PFX##s1 = 0.f, PFX##s2 = 0.f, PFX##s3 = 0.f;           \
  DOT4P(PFX, PFX##P0, 0) DOT4P(PFX, PFX##P1, 4)                               \
  DOT4P(PFX, PFX##P2, 8) DOT4P(PFX, PFX##P3, 12)                              \
  DOT4P(PFX, PFX##P4, 16) DOT4P(PFX, PFX##P5, 20)                             \
  DOT4P(PFX, PFX##P6, 24) DOT4P(PFX, PFX##P7, 28)                             \
  W = ((PFX##s0 + PFX##s1) + (PFX##s2 + PFX##s3)) * (PFX##K * (EF));

// sched_barrier(0): hard scheduler fence — the 2 LDS writes + 16 broadcast
// reads MUST stay above all dot2s. This is what stops the machine scheduler
// from sinking the reads to their uses (R6's serialization failure). Chain X's
// dot2s then run on lgkmcnt(8)-style partial waits while Y's reads land.
#define STEP_PAIR(EF0, EF1)                                                   \
  {                                                                           \
    CRF_BCAST(X_, w0, lb0, lbv0)                                              \
    CRF_BCAST(Y_, w1, lb1, lbv1)                                              \
    __builtin_amdgcn_sched_barrier(0);                                        \
    CRF_MATVEC(X_, w0, e20, EF0)                                              \
    CRF_MATVEC(Y_, w1, e21, EF1)                                              \
  }

// Blocks 0..127: fwd chains of batches (2j,2j+1) — SAME direction => one
// shared R table (batch-independent). Blocks 128..255: bwd chains of
// (2j,2j+1). Blocks 256..511: gold path.
__global__ __launch_bounds__(64)
__attribute__((amdgpu_waves_per_eu(1, 1)))  // target occupancy 1 wave/EU:
                                            // frees the scheduler from
                                            // pressure-driven load sinking
void fb_kernel(const float* __restrict__ scores,
               const int* __restrict__ targets,
               const float* __restrict__ start,
               const float* __restrict__ Tm,
               const float* __restrict__ endv,
               float* __restrict__ wsA,
               float* __restrict__ wsB,
               float* __restrict__ wsG) {
  const int lane = threadIdx.x;
  const int bb = blockIdx.x;

  if (bb >= 2 * PB) {  // ---- gold path: one wave per batch ----
    const int b = bb - 2 * PB;
    const int* tg = targets + b * NT;
    const float* sc = scores + (size_t)b * NT * NL;
    float acc = 0.f;
    for (int t = lane; t < NT; t += 64) {
      int c = tg[t];
      acc += sc[t * NL + c];
      if (t > 0) acc += Tm[c * NL + tg[t - 1]];  // T_mat[cur, prev]
    }
#pragma unroll
    for (int off = 32; off > 0; off >>= 1) acc += __shfl_xor(acc, off, 64);
    if (lane == 0) wsG[b] = acc + start[tg[0]] + endv[tg[NT - 1]];
    return;
  }

  __shared__ int4 lds_s[32];  // words 0..63 = chain-X buffer, 64..127 = chain-Y
  int* lb0 = (int*)lds_s;
  int* lb1 = (int*)(lds_s + 16);
  const int4* lbv0 = lds_s;
  const int4* lbv1 = lds_s + 16;
  const int slot = (lane & 1) * 32 + (lane >> 1);  // 2 lanes/bank write -> free

  const bool bwd = bb >= PB;
  const int bp = bwd ? bb - PB : bb;
  const int b0 = 2 * bp, b1 = 2 * bp + 1;
  const float* sc0 = scores + (size_t)b0 * NT * NL;
  const float* sc1 = scores + (size_t)b1 * NT * NL;
  const float LN2 = 0.69314718055994530942f;

  // shared f16x2 table: fwd R[k] = (exp(T[lane][2k]), exp(T[lane][2k+1]))
  //                     bwd R[k] = (exp(T[2k][lane]), exp(T[2k+1][lane]))
  const float* Tb = bwd ? (Tm + lane) : (Tm + lane * NL);
  const int str = bwd ? NL : 1;
  h2v R[32];
#pragma unroll
  for (int k = 0; k < 32; k++)
    R[k] = __builtin_amdgcn_cvt_pkrtz(__expf(Tb[(2 * k) * str]),
                                      __expf(Tb[(2 * k + 1) * str]));

  float w0, w1, m00, m01;
  int e20, e21;
  if (!bwd) {
    float a0 = start[lane] + sc0[lane];
    float a1 = start[lane] + sc1[lane];
    m00 = rfl_f(a0); m01 = rfl_f(a1);
    w0 = __expf(a0 - m00) * 16.f; w1 = __expf(a1 - m01) * 16.f;
  } else {
    float a0 = endv[lane] + sc0[(NT - 1) * NL + lane];
    float a1 = endv[lane] + sc1[(NT - 1) * NL + lane];
    m00 = rfl_f(a0); m01 = rfl_f(a1);
    w0 = __expf(a0 - m00) * 16.f; w1 = __expf(a1 - m01) * 16.f;
  }
  e20 = -4; e21 = -4;

  if (!bwd) {
    float buf0[4], buf1[4];
#pragma unroll
    for (int k = 0; k < 4; k++) {
      buf0[k] = sc0[(1 + k) * NL + lane];
      buf1[k] = sc1[(1 + k) * NL + lane];
    }
    for (int i = 0; i < 128; i++) {  // 512 steps: t = 1..512
      float nb0[4], nb1[4];
      int tf = 5 + 4 * i;  // prefetch (max 513..516 < 1024)
#pragma unroll
      for (int k = 0; k < 4; k++) {
        nb0[k] = sc0[(tf + k) * NL + lane];
        nb1[k] = sc1[(tf + k) * NL + lane];
      }
      float Ev0[4], Ev1[4];
#pragma unroll
      for (int k = 0; k < 4; k++) {
        Ev0[k] = __expf(buf0[k]);  // off critical chain
        Ev1[k] = __expf(buf1[k]);
      }
      STEP_PAIR(Ev0[0], Ev1[0])
      STEP_PAIR(Ev0[1], Ev1[1])
      STEP_PAIR(Ev0[2], Ev1[2])
      STEP_PAIR(Ev0[3], Ev1[3])
#pragma unroll
      for (int k = 0; k < 4; k++) {
        buf0[k] = nb0[k];
        buf1[k] = nb1[k];
      }
    }
    // alpha_512, transposed [state][batch]; 512 steps: fold -3/step ledger.
    wsA[lane * NB + b0] = m00 + (float)(e20 - 3 * 512) * LN2 + __logf(w0);
    wsA[lane * NB + b1] = m01 + (float)(e21 - 3 * 512) * LN2 + __logf(w1);
  } else {
    float buf0[4], buf1[4];
#pragma unroll
    for (int k = 0; k < 4; k++) {
      buf0[k] = sc0[(1022 - k) * NL + lane];
      buf1[k] = sc1[(1022 - k) * NL + lane];
    }
    for (int i = 0; i < 127; i++) {  // 508 steps: te = 1022..515
      float nb0[4], nb1[4];
      int tb = 1018 - 4 * i;  // prefetch (min 514..511 >= 0)
#pragma unroll
      for (int k = 0; k < 4; k++) {
        nb0[k] = sc0[(tb - k) * NL + lane];
        nb1[k] = sc1[(tb - k) * NL + lane];
      }
      float Ev0[4], Ev1[4];
#pragma unroll
      for (int k = 0; k < 4; k++) {
        Ev0[k] = __expf(buf0[k]);
        Ev1[k] = __expf(buf1[k]);
      }
      STEP_PAIR(Ev0[0], Ev1[0])
      STEP_PAIR(Ev0[1], Ev1[1])
      STEP_PAIR(Ev0[2], Ev1[2])
      STEP_PAIR(Ev0[3], Ev1[3])
#pragma unroll
      for (int k = 0; k < 4; k++) {
        buf0[k] = nb0[k];
        buf1[k] = nb1[k];
      }
    }
    // tails: buf = emits te = 514, 513 (slots 0,1); then final E=1 step.
    {
      float E0 = __expf(buf0[0]), E1 = __expf(buf1[0]);
      STEP_PAIR(E0, E1)
    }
    {
      float E0 = __expf(buf0[1]), E1 = __expf(buf1[1]);
      STEP_PAIR(E0, E1)
    }
    STEP_PAIR(1.0f, 1.0f)  // matvec-only -> beta_512 (emit_512 is alpha-side)
    // beta_512, transposed; 511 steps: fold -3/step ledger.
    wsB[lane * NB + b0] = m00 + (float)(e20 - 3 * 511) * LN2 + __logf(w0);
    wsB[lane * NB + b1] = m01 + (float)(e21 - 3 * 511) * LN2 + __logf(w1);
  }
}

// thread b handles batch b: lse over 64 states (coalesced via transposed ws layout),
// subtract gold, block-reduce mean.
__global__ __launch_bounds__(256) void combine_kernel(const float* __restrict__ wsA,
                                                      const float* __restrict__ wsB,
                                                      const float* __restrict__ wsG,
                                                      float* __restrict__ out) {
  const int b = threadIdx.x;
  float m = -INFINITY;
#pragma unroll
  for (int j = 0; j < NL; j++) m = fmaxf(m, wsA[j * NB + b] + wsB[j * NB + b]);
  float s = 0.f;
#pragma unroll
  for (int j = 0; j < NL; j++) s += __expf(wsA[j * NB + b] + wsB[j * NB + b] - m);
  float loss = (m + __logf(s)) - wsG[b];
#pragma unroll
  for (int off = 32; off > 0; off >>= 1) loss += __shfl_xor(loss, off, 64);
  __shared__ float red[4];
  if ((b & 63) == 0) red[b >> 6] = loss;
  __syncthreads();
  if (b == 0) out[0] = (red[0] + red[1] + red[2] + red[3]) * (1.0f / NB);
}

extern "C" void kernel_launch(void* const* d_in, const int* in_sizes, int n_in,
                              void* d_out, int out_size, void* d_ws, size_t ws_size,
                              hipStream_t stream) {
  const float* scores = (const float*)d_in[0];
  const int* targets = (const int*)d_in[1];
  const float* start = (const float*)d_in[2];
  const float* Tm = (const float*)d_in[3];
  const float* endv = (const float*)d_in[4];
  float* out = (float*)d_out;

  float* wsA = (float*)d_ws;       // [NL*NB] alpha_512, transposed [state][batch]
  float* wsB = wsA + NB * NL;      // [NL*NB] beta_512, transposed
  float* wsG = wsB + NB * NL;      // [NB] gold path scores

  fb_kernel<<<2 * PB + NB, 64, 0, stream>>>(scores, targets, start, Tm, endv, wsA, wsB, wsG);
  combine_kernel<<<1, 256, 0, stream>>>(wsA, wsB, wsG, out);
}

// Round 8
// 182.577 us; speedup vs baseline: 1.6103x; 1.2700x over previous
//
#include <hip/hip_runtime.h>

#define NB 256
#define NT 1024
#define NL 64

typedef __fp16 h2v __attribute__((ext_vector_type(2)));

__device__ __forceinline__ float rfl_f(float v) {
  return __builtin_bit_cast(float, __builtin_amdgcn_readfirstlane(__builtin_bit_cast(int, v)));
}

// partner = value from lane^1, via DPP quad_perm [1,0,3,2] (VALU, no LDS pipe)
__device__ __forceinline__ float dpp_xor1(float v) {
  int i = __builtin_bit_cast(int, v);
  int r = __builtin_amdgcn_update_dpp(i, i, 0xB1, 0xF, 0xF, false);
  return __builtin_bit_cast(float, r);
}

#define DOT4(P, B)                                                            \
  s0 = __builtin_amdgcn_fdot2(__builtin_bit_cast(h2v, (P).x), Rh[(B) + 0], s0, false); \
  s1 = __builtin_amdgcn_fdot2(__builtin_bit_cast(h2v, (P).y), Rh[(B) + 1], s1, false); \
  s2 = __builtin_amdgcn_fdot2(__builtin_bit_cast(h2v, (P).z), Rh[(B) + 2], s2, false); \
  s3 = __builtin_amdgcn_fdot2(__builtin_bit_cast(h2v, (P).w), Rh[(B) + 3], s3, false);

// One CRF step, LDS-broadcast version (R4 structure, scheduling pinned):
//  - pack (w, partner) -> f16x2, 1 b32 LDS write, 8 uniform-address
//    (broadcast) b128 reads; sched_barrier(0) pins write+reads ABOVE the
//    dots so the machine scheduler cannot sink the reads to their uses
//    (R6's failure mode) — dots then run on fine-grained lgkmcnt.
//  - renorm scale K = 2^(3-e5) from pair0's f16 exponent: uniform, pure
//    VALU, computed in the read-shadow (off the dot critical path).
#define CRF_STEP(EF)                                                          \
  do {                                                                        \
    float wn = dpp_xor1(w);                                                   \
    h2v pk = __builtin_amdgcn_cvt_pkrtz(w, wn);                               \
    lb[wslot] = __builtin_bit_cast(int, pk);                                  \
    int4 P0 = lbv[0], P1 = lbv[1], P2 = lbv[2], P3 = lbv[3];                  \
    int4 P4 = lbv[4], P5 = lbv[5], P6 = lbv[6], P7 = lbv[7];                  \
    __builtin_amdgcn_sched_barrier(0);                                        \
    int e5 = (P0.x >> 10) & 0x1f;                                             \
    float K = __builtin_bit_cast(float, (130 - e5) << 23);                    \
    float KE = K * (EF);                                                      \
    e2 += e5;                                                                 \
    float s0 = 0.f, s1 = 0.f, s2 = 0.f, s3 = 0.f;                             \
    DOT4(P0, 0); DOT4(P1, 4); DOT4(P2, 8); DOT4(P3, 12);                      \
    DOT4(P4, 16); DOT4(P5, 20); DOT4(P6, 24); DOT4(P7, 28);                   \
    w = ((s0 + s1) + (s2 + s3)) * KE;                                         \
  } while (0)

// Blocks 0..255: forward chains. 256..511: backward chains. 512..767: gold.
__global__ __launch_bounds__(64)
__attribute__((amdgpu_waves_per_eu(1, 1)))  // kill pressure-driven load sinking
void fb_kernel(const float* __restrict__ scores,
               const int* __restrict__ targets,
               const float* __restrict__ start,
               const float* __restrict__ Tm,
               const float* __restrict__ endv,
               float* __restrict__ wsA,
               float* __restrict__ wsB,
               float* __restrict__ wsG) {
  const int lane = threadIdx.x;
  const int bb = blockIdx.x;

  if (bb >= 2 * NB) {  // ---- gold path: one wave per batch ----
    const int b = bb - 2 * NB;
    const int* tg = targets + b * NT;
    const float* sc = scores + (size_t)b * NT * NL;
    float acc = 0.f;
    for (int t = lane; t < NT; t += 64) {
      int c = tg[t];
      acc += sc[t * NL + c];
      if (t > 0) acc += Tm[c * NL + tg[t - 1]];  // T_mat[cur, prev]
    }
#pragma unroll
    for (int off = 32; off > 0; off >>= 1) acc += __shfl_xor(acc, off, 64);
    if (lane == 0) wsG[b] = acc + start[tg[0]] + endv[tg[NT - 1]];
    return;
  }

  __shared__ int4 lbv_s[16];        // 64 words: 0..31 = consumed pairs, 32..63 = scratch
  int* lb = (int*)lbv_s;
  const int4* lbv = lbv_s;
  const int wslot = (lane & 1) * 32 + (lane >> 1);  // 2 lanes/bank -> conflict-free

  const bool bwd = bb >= NB;
  const int b = bwd ? bb - NB : bb;
  const float* sc = scores + (size_t)b * NT * NL;
  const float LN2 = 0.69314718055994530942f;

  // f16x2 transition table: fwd Rh[k] = (exp(T[lane][2k]), exp(T[lane][2k+1]))
  //                         bwd Rh[k] = (exp(T[2k][lane]), exp(T[2k+1][lane]))
  const float* Tb = bwd ? (Tm + lane) : (Tm + lane * NL);
  const int str = bwd ? NL : 1;
  h2v Rh[32];
#pragma unroll
  for (int k = 0; k < 32; k++)
    Rh[k] = __builtin_amdgcn_cvt_pkrtz(__expf(Tb[(2 * k) * str]),
                                       __expf(Tb[(2 * k + 1) * str]));

  if (!bwd) {
    float a0 = start[lane] + sc[lane];  // alpha_0
    float m0 = rfl_f(a0);
    float w = __expf(a0 - m0) * 16.f;   // keep w_0 in f16-normal range
    int e2 = -4;

    float buf[4];
#pragma unroll
    for (int k = 0; k < 4; k++) buf[k] = sc[(1 + k) * NL + lane];

    for (int i = 0; i < 128; i++) {  // 512 steps: t = 1..512
      float nb4[4];
      int tb = 5 + 4 * i;  // prefetch (max t=516 < 1024)
#pragma unroll
      for (int k = 0; k < 4; k++) nb4[k] = sc[(tb + k) * NL + lane];
      __builtin_amdgcn_sched_barrier(0);  // pin prefetch at iter top:
                                          // ~1800-cyc cover before vmcnt wait
      float Ev[4];
#pragma unroll
      for (int k = 0; k < 4; k++) Ev[k] = __expf(buf[k]);  // off critical chain
      CRF_STEP(Ev[0]);
      CRF_STEP(Ev[1]);
      CRF_STEP(Ev[2]);
      CRF_STEP(Ev[3]);
#pragma unroll
      for (int k = 0; k < 4; k++) buf[k] = nb4[k];
    }
    // alpha_512 (transposed); e2 accumulated raw e5: fold -3/step ledger.
    wsA[lane * NB + b] = m0 + (float)(e2 - 3 * 512) * LN2 + __logf(w);
  } else {
    float a0 = endv[lane] + sc[(NT - 1) * NL + lane];
    float m0 = rfl_f(a0);
    float w = __expf(a0 - m0) * 16.f;
    int e2 = -4;

    float buf[4];
#pragma unroll
    for (int k = 0; k < 4; k++) buf[k] = sc[(1022 - k) * NL + lane];

    for (int i = 0; i < 127; i++) {  // 508 steps: te = 1022..515
      float nb4[4];
      int tb = 1018 - 4 * i;  // prefetch (min 511 >= 0)
#pragma unroll
      for (int k = 0; k < 4; k++) nb4[k] = sc[(tb - k) * NL + lane];
      __builtin_amdgcn_sched_barrier(0);
      float Ev[4];
#pragma unroll
      for (int k = 0; k < 4; k++) Ev[k] = __expf(buf[k]);
      CRF_STEP(Ev[0]);
      CRF_STEP(Ev[1]);
      CRF_STEP(Ev[2]);
      CRF_STEP(Ev[3]);
#pragma unroll
      for (int k = 0; k < 4; k++) buf[k] = nb4[k];
    }
    CRF_STEP(__expf(sc[514 * NL + lane]));
    CRF_STEP(__expf(sc[513 * NL + lane]));
    CRF_STEP(1.0f);  // final matvec-only step -> beta_512
    // beta_512 (transposed); 511 steps: fold -3/step ledger.
    wsB[lane * NB + b] = m0 + (float)(e2 - 3 * 511) * LN2 + __logf(w);
  }
}

// thread b handles batch b: lse over 64 states (coalesced via transposed ws layout),
// subtract gold, block-reduce mean.
__global__ __launch_bounds__(256) void combine_kernel(const float* __restrict__ wsA,
                                                      const float* __restrict__ wsB,
                                                      const float* __restrict__ wsG,
                                                      float* __restrict__ out) {
  const int b = threadIdx.x;
  float m = -INFINITY;
#pragma unroll
  for (int j = 0; j < NL; j++) m = fmaxf(m, wsA[j * NB + b] + wsB[j * NB + b]);
  float s = 0.f;
#pragma unroll
  for (int j = 0; j < NL; j++) s += __expf(wsA[j * NB + b] + wsB[j * NB + b] - m);
  float loss = (m + __logf(s)) - wsG[b];
#pragma unroll
  for (int off = 32; off > 0; off >>= 1) loss += __shfl_xor(loss, off, 64);
  __shared__ float red[4];
  if ((b & 63) == 0) red[b >> 6] = loss;
  __syncthreads();
  if (b == 0) out[0] = (red[0] + red[1] + red[2] + red[3]) * (1.0f / NB);
}

extern "C" void kernel_launch(void* const* d_in, const int* in_sizes, int n_in,
                              void* d_out, int out_size, void* d_ws, size_t ws_size,
                              hipStream_t stream) {
  const float* scores = (const float*)d_in[0];
  const int* targets = (const int*)d_in[1];
  const float* start = (const float*)d_in[2];
  const float* Tm = (const float*)d_in[3];
  const float* endv = (const float*)d_in[4];
  float* out = (float*)d_out;

  float* wsA = (float*)d_ws;       // [NL*NB] alpha_512, transposed [state][batch]
  float* wsB = wsA + NB * NL;      // [NL*NB] beta_512, transposed
  float* wsG = wsB + NB * NL;      // [NB] gold path scores

  fb_kernel<<<3 * NB, 64, 0, stream>>>(scores, targets, start, Tm, endv, wsA, wsB, wsG);
  combine_kernel<<<1, 256, 0, stream>>>(wsA, wsB, wsG, out);
}